// Round 3
// baseline (144.577 us; speedup 1.0000x reference)
//
#include <hip/hip_runtime.h>

#define B 32
#define E 256
#define N 64
#define KV 100
#define QD 768

// ---------------------------------------------------------------------------
// Prep: blocks 0..31 -> Qk[b][j] = 0.1 * sum_i tanh(q[b]@W_q[i]+b_q[i]) * W_kv[i][j]
// ---------------------------------------------------------------------------
__global__ __launch_bounds__(256) void prep_kernel(
    const float* __restrict__ q,      // [B, QD]
    const float* __restrict__ W_q,    // [KV, QD]
    const float* __restrict__ b_q,    // [KV]
    const float* __restrict__ W_kv,   // [KV, KV]
    float* __restrict__ Qk)           // ws: [B, KV]
{
    const int tid = threadIdx.x;
    const int b   = blockIdx.x;

    __shared__ float q_lds[QD];
    __shared__ float Qp_lds[KV];

    for (int i = tid; i < QD; i += 256) q_lds[i] = q[b * QD + i];
    __syncthreads();

    // Qp[i] = tanh(dot(q[b], W_q[i]) + b_q[i]); 2 threads per output
    const int i = tid >> 1, h = tid & 1;
    if (i < KV) {
        float acc = 0.f;
        const float* wrow = W_q + i * QD + h * (QD / 2);
        const float* qrow = q_lds + h * (QD / 2);
        #pragma unroll 8
        for (int d = 0; d < QD / 2; d++) acc += qrow[d] * wrow[d];
        acc += __shfl_xor(acc, 1);
        if (h == 0) Qp_lds[i] = tanhf(acc + b_q[i]);
    }
    __syncthreads();

    // Qk[b][j] = (1/sqrt(KV)) * sum_i Qp[i] * W_kv[i][j]
    if (tid < KV) {
        float acc = 0.f;
        #pragma unroll 4
        for (int ii = 0; ii < KV; ii++) acc += Qp_lds[ii] * W_kv[ii * KV + tid];
        Qk[b * KV + tid] = acc * 0.1f;   // 1/sqrt(100)
    }
}

// ---------------------------------------------------------------------------
// K1: pure k-stream. One 4-lane quad per (b,e,n) row; no LDS, no barriers.
// Emits leaky_relu(masked_fill(score)) ready for softmax.
// ---------------------------------------------------------------------------
__global__ __launch_bounds__(256) void score_kernel(
    const float* __restrict__ k,        // [B,E,N,KV]
    const float* __restrict__ Qk,       // [B,KV] (pre-scaled)
    float* __restrict__ att_raw)        // ws: [B*E*N]
{
    const int tid  = threadIdx.x;
    const int quad = tid >> 2, sub = tid & 3;
    const int r    = blockIdx.x * 64 + quad;     // row id, 64 rows/block
    const int b    = r >> 14;                    // / (E*N) = 16384

    const float4* krow = (const float4*)(k + (size_t)r * KV);
    const float4* qk4  = (const float4*)(Qk + b * KV);   // L1-resident

    float acc = 0.f;
    #pragma unroll
    for (int j = sub; j < KV / 4; j += 4) {
        float4 kk = krow[j];
        float4 qq = qk4[j];
        acc += qq.x * kk.x + qq.y * kk.y + qq.z * kk.z + qq.w * kk.w;
    }
    acc += __shfl_xor(acc, 1);
    acc += __shfl_xor(acc, 2);
    if (sub == 0) {
        float a = acc;                       // already scaled by 1/sqrt(KV)
        if (a == 0.0f) a = -10000.0f;        // masked_fill(att==0, -1e4)
        a = (a > 0.0f) ? a : 0.01f * a;      // leaky_relu
        att_raw[r] = a;                      // quads -> contiguous 64B/wave
    }
}

// ---------------------------------------------------------------------------
// K2: per (b,e): v-loads issued FIRST (regs), softmax hides under them,
// FMA from regs, LDS reduce, vectorized projection via W_v rows.
// ---------------------------------------------------------------------------
__global__ __launch_bounds__(256) void agg_kernel(
    const float* __restrict__ v,        // [B,E,N,KV]
    const float* __restrict__ att_raw,  // ws: [B*E*N]
    const float* __restrict__ W_v,      // [KV,KV] (rows, no transpose)
    float* __restrict__ out)            // [B,E,KV]
{
    __shared__ float att_lds[N];
    __shared__ __align__(16) float part_lds[8][KV];
    __shared__ __align__(16) float agg_lds[KV];

    const int tid = threadIdx.x;
    const int be  = blockIdx.x;

    // ---- A: issue all v loads into registers (independent, no wait) ----
    const bool active = tid < 200;
    const int  c  = tid % 25;            // float4 column
    const int  ng = tid / 25;            // n-group of 8
    float4 vr[8];
    if (active) {
        const float4* vb = (const float4*)(v + (size_t)be * (N * KV));
        #pragma unroll
        for (int i = 0; i < 8; i++)
            vr[i] = vb[(ng * 8 + i) * (KV / 4) + c];
    }

    // ---- B: softmax over N=64 in wave 0 (runs under v-load latency) ----
    if (tid < 64) {
        float x = att_raw[(size_t)be * N + tid];
        float m = x;
        #pragma unroll
        for (int o = 32; o; o >>= 1) m = fmaxf(m, __shfl_xor(m, o));
        float e = __expf(x - m);
        float s = e;
        #pragma unroll
        for (int o = 32; o; o >>= 1) s += __shfl_xor(s, o);
        float r = e / s;
        if (r == 0.015625f) r = 0.0f;        // masked_fill(att==1/N, 0)
        att_lds[tid] = r;
    }
    __syncthreads();

    // ---- C: weighted sum from registers ----
    if (active) {
        float4 a4 = make_float4(0.f, 0.f, 0.f, 0.f);
        #pragma unroll
        for (int i = 0; i < 8; i++) {
            float w = att_lds[ng * 8 + i];
            a4.x += w * vr[i].x;
            a4.y += w * vr[i].y;
            a4.z += w * vr[i].z;
            a4.w += w * vr[i].w;
        }
        *(float4*)&part_lds[ng][c * 4] = a4;
    }
    __syncthreads();

    if (tid < KV) {
        float s = 0.f;
        #pragma unroll
        for (int g = 0; g < 8; g++) s += part_lds[g][tid];
        agg_lds[tid] = s;
    }
    __syncthreads();

    // ---- D: out[be][i] = dot(W_v row i, agg); 2 lanes per output ----
    const int p = tid >> 1, h = tid & 1;
    if (p < KV) {
        const float4* wrow = (const float4*)(W_v + p * KV);   // rows 16B-aligned
        const float4* a4   = (const float4*)agg_lds;
        float acc = 0.f;
        #pragma unroll
        for (int j = h; j < KV / 4; j += 2) {
            float4 w = wrow[j];
            float4 a = a4[j];
            acc += w.x * a.x + w.y * a.y + w.z * a.z + w.w * a.w;
        }
        acc += __shfl_xor(acc, 1);
        if (h == 0) out[(size_t)be * KV + p] = acc;
    }
}

extern "C" void kernel_launch(void* const* d_in, const int* in_sizes, int n_in,
                              void* d_out, int out_size, void* d_ws, size_t ws_size,
                              hipStream_t stream) {
    // setup_inputs order: input_ent, q, k, v, W_q, b_q, W_kv, W_v
    const float* q    = (const float*)d_in[1];
    const float* k    = (const float*)d_in[2];
    const float* v    = (const float*)d_in[3];
    const float* W_q  = (const float*)d_in[4];
    const float* b_q  = (const float*)d_in[5];
    const float* W_kv = (const float*)d_in[6];
    const float* W_v  = (const float*)d_in[7];
    float* out  = (float*)d_out;

    float* Qk      = (float*)d_ws;           // B*KV = 3200 floats (12.8 KB)
    float* att_raw = Qk + B * KV;            // B*E*N = 524288 floats (2 MB)

    prep_kernel<<<B, 256, 0, stream>>>(q, W_q, b_q, W_kv, Qk);
    score_kernel<<<(B * E * N) / 64, 256, 0, stream>>>(k, Qk, att_raw);
    agg_kernel<<<B * E, 256, 0, stream>>>(v, att_raw, W_v, out);
}

// Round 4
// 143.092 us; speedup vs baseline: 1.0104x; 1.0104x over previous
//
#include <hip/hip_runtime.h>

#define B 32
#define E 256
#define N 64
#define KV 100
#define QD 768

// ---------------------------------------------------------------------------
// Prep: blocks 0..31 -> Qk[b][j] = 0.1 * sum_i tanh(q[b]@W_q[i]+b_q[i]) * W_kv[i][j]
// ---------------------------------------------------------------------------
__global__ __launch_bounds__(256) void prep_kernel(
    const float* __restrict__ q,      // [B, QD]
    const float* __restrict__ W_q,    // [KV, QD]
    const float* __restrict__ b_q,    // [KV]
    const float* __restrict__ W_kv,   // [KV, KV]
    float* __restrict__ Qk)           // ws: [B, KV]
{
    const int tid = threadIdx.x;
    const int b   = blockIdx.x;

    __shared__ float q_lds[QD];
    __shared__ float Qp_lds[KV];

    for (int i = tid; i < QD; i += 256) q_lds[i] = q[b * QD + i];
    __syncthreads();

    // Qp[i] = tanh(dot(q[b], W_q[i]) + b_q[i]); 2 threads per output
    const int i = tid >> 1, h = tid & 1;
    if (i < KV) {
        float acc = 0.f;
        const float* wrow = W_q + i * QD + h * (QD / 2);
        const float* qrow = q_lds + h * (QD / 2);
        #pragma unroll 8
        for (int d = 0; d < QD / 2; d++) acc += qrow[d] * wrow[d];
        acc += __shfl_xor(acc, 1);
        if (h == 0) Qp_lds[i] = tanhf(acc + b_q[i]);
    }
    __syncthreads();

    // Qk[b][j] = (1/sqrt(KV)) * sum_i Qp[i] * W_kv[i][j]
    if (tid < KV) {
        float acc = 0.f;
        #pragma unroll 4
        for (int ii = 0; ii < KV; ii++) acc += Qp_lds[ii] * W_kv[ii * KV + tid];
        Qk[b * KV + tid] = acc * 0.1f;   // 1/sqrt(100)
    }
}

// ---------------------------------------------------------------------------
// Fused main: one block per (b,e). ALL global loads (k-quad rows, v rows)
// issue up-front into registers -> a single latency window at the first
// barrier. Then: scores(regs) -> softmax(wave0) -> v-FMA(regs) -> reduce ->
// projection (W_v stays L2-resident).
// ---------------------------------------------------------------------------
__global__ __launch_bounds__(256) void attn_kernel(
    const float* __restrict__ k,    // [B,E,N,KV]
    const float* __restrict__ v,    // [B,E,N,KV]
    const float* __restrict__ Qk,   // [B,KV] (pre-scaled by 1/sqrt(KV))
    const float* __restrict__ W_v,  // [KV,KV]
    float* __restrict__ out)        // [B,E,KV]
{
    __shared__ __align__(16) float qk_lds[KV];
    __shared__ float att_lds[N];
    __shared__ __align__(16) float part_lds[8][KV];
    __shared__ __align__(16) float agg_lds[KV];

    const int tid = threadIdx.x;
    const int be  = blockIdx.x;       // 0..B*E-1
    const int b   = be >> 8;          // /E

    const float4* kbase = (const float4*)(k + (size_t)be * (N * KV));
    const float4* vbase = (const float4*)(v + (size_t)be * (N * KV));

    // ---- Phase 0: issue ALL global loads back-to-back ----
    // k: 4 lanes per row n, lane sub takes float4 j = sub, sub+4, ...
    const int n = tid >> 2, sub = tid & 3;
    float4 kr[7];
    {
        int idx = 0;
        #pragma unroll
        for (int j = sub; j < KV / 4; j += 4)
            kr[idx++] = kbase[n * (KV / 4) + j];
    }
    // v: 200 threads, thread = (n-group of 8) x (float4 column)
    const bool vact = tid < 200;
    const int  c  = tid % 25;
    const int  ng = tid / 25;
    float4 vr[8];
    if (vact) {
        #pragma unroll
        for (int i = 0; i < 8; i++)
            vr[i] = vbase[(ng * 8 + i) * (KV / 4) + c];
    }
    // Qk -> LDS (L2-resident, tiny)
    if (tid < KV / 4)
        ((float4*)qk_lds)[tid] = ((const float4*)(Qk + b * KV))[tid];

    __syncthreads();   // single drain point for all of the above

    // ---- Phase 1: scores from registers ----
    {
        float acc = 0.f;
        int idx = 0;
        #pragma unroll
        for (int j = sub; j < KV / 4; j += 4) {
            float4 kk = kr[idx++];
            acc += qk_lds[4 * j + 0] * kk.x + qk_lds[4 * j + 1] * kk.y
                 + qk_lds[4 * j + 2] * kk.z + qk_lds[4 * j + 3] * kk.w;
        }
        acc += __shfl_xor(acc, 1);
        acc += __shfl_xor(acc, 2);
        if (sub == 0) {
            float a = acc;                      // already scaled by 1/sqrt(KV)
            if (a == 0.0f) a = -10000.0f;       // masked_fill(att==0, -1e4)
            a = (a > 0.0f) ? a : 0.01f * a;     // leaky_relu
            att_lds[n] = a;
        }
    }
    __syncthreads();

    // ---- Phase 2: softmax over N=64 in wave 0 ----
    if (tid < 64) {
        float x = att_lds[tid];
        float m = x;
        #pragma unroll
        for (int o = 32; o; o >>= 1) m = fmaxf(m, __shfl_xor(m, o));
        float e = __expf(x - m);
        float s = e;
        #pragma unroll
        for (int o = 32; o; o >>= 1) s += __shfl_xor(s, o);
        float r = e / s;
        if (r == 0.015625f) r = 0.0f;           // masked_fill(att==1/N, 0)
        att_lds[tid] = r;
    }
    __syncthreads();

    // ---- Phase 3: weighted v-sum from registers ----
    if (vact) {
        float4 a4 = make_float4(0.f, 0.f, 0.f, 0.f);
        #pragma unroll
        for (int i = 0; i < 8; i++) {
            float w = att_lds[ng * 8 + i];
            a4.x += w * vr[i].x;
            a4.y += w * vr[i].y;
            a4.z += w * vr[i].z;
            a4.w += w * vr[i].w;
        }
        *(float4*)&part_lds[ng][c * 4] = a4;
    }
    __syncthreads();

    if (tid < KV) {
        float s = 0.f;
        #pragma unroll
        for (int g = 0; g < 8; g++) s += part_lds[g][tid];
        agg_lds[tid] = s;
    }
    __syncthreads();

    // ---- Phase 4: out[be][i] = dot(W_v row i, agg); 2 lanes per output ----
    const int p = tid >> 1, h = tid & 1;
    if (p < KV) {
        const float4* wrow = (const float4*)(W_v + p * KV);  // L2-resident
        const float4* a4   = (const float4*)agg_lds;
        float acc = 0.f;
        #pragma unroll
        for (int j = h; j < KV / 4; j += 2) {
            float4 w = wrow[j];
            float4 a = a4[j];
            acc += w.x * a.x + w.y * a.y + w.z * a.z + w.w * a.w;
        }
        acc += __shfl_xor(acc, 1);
        if (h == 0) out[(size_t)be * KV + p] = acc;
    }
}

extern "C" void kernel_launch(void* const* d_in, const int* in_sizes, int n_in,
                              void* d_out, int out_size, void* d_ws, size_t ws_size,
                              hipStream_t stream) {
    // setup_inputs order: input_ent, q, k, v, W_q, b_q, W_kv, W_v
    const float* q    = (const float*)d_in[1];
    const float* k    = (const float*)d_in[2];
    const float* v    = (const float*)d_in[3];
    const float* W_q  = (const float*)d_in[4];
    const float* b_q  = (const float*)d_in[5];
    const float* W_kv = (const float*)d_in[6];
    const float* W_v  = (const float*)d_in[7];
    float* out  = (float*)d_out;

    float* Qk = (float*)d_ws;            // B*KV = 3200 floats

    prep_kernel<<<B, 256, 0, stream>>>(q, W_q, b_q, W_kv, Qk);
    attn_kernel<<<B * E, 256, 0, stream>>>(k, v, Qk, W_v, out);
}